// Round 12
// baseline (363.345 us; speedup 1.0000x reference)
//
#include <hip/hip_runtime.h>
#include <stdint.h>
#include <math.h>

#define D_MODEL 1024
#define NHEAD   16
#define HDIM    64
#define FFDIM   4096
#define SEQ     2048
#define BATCH   2
#define NTOK    (BATCH*SEQ)
#define QKVN    (3*D_MODEL)

typedef __bf16 bf16;
typedef __attribute__((ext_vector_type(8))) __bf16 bf16x8;
typedef __attribute__((ext_vector_type(4))) __bf16 bf16x4;
typedef __attribute__((ext_vector_type(4))) float f32x4;

__device__ __forceinline__ void gld_lds16(const void* g, void* l) {
    __builtin_amdgcn_global_load_lds((__attribute__((address_space(1))) void*)g,
                                     (__attribute__((address_space(3))) void*)l,
                                     16, 0, 0);
}

__device__ __forceinline__ float fast_exp2(float x) {
#if __has_builtin(__builtin_amdgcn_exp2f)
    return __builtin_amdgcn_exp2f(x);
#else
    return __expf(x * 0.69314718056f);
#endif
}

__device__ __forceinline__ float fast_rcp(float x) {
#if __has_builtin(__builtin_amdgcn_rcpf)
    return __builtin_amdgcn_rcpf(x);
#else
    return 1.0f / x;
#endif
}

// tanh-form GELU: max |err vs erf-gelu| ~3e-4, below bf16 output quantization.
__device__ __forceinline__ float gelu_fast(float x) {
    float xx = x * x;
    float y  = x * fmaf(0.035677408137f, xx, 0.7978845608f);
    float z  = fminf(-2.8853900817779268f * y, 126.0f);
    float e  = fast_exp2(z);
    return x * fast_rcp(1.0f + e);
}

#define BARRIER() do {                                         \
    __builtin_amdgcn_s_barrier();                              \
    asm volatile("" ::: "memory");                             \
} while (0)
#define LGKM0() asm volatile("s_waitcnt lgkmcnt(0)" ::: "memory")
#define VMW(N)  asm volatile("s_waitcnt vmcnt(" #N ")" ::: "memory")

// ---------------- all 4 weight transposes (fp32 W[K][N] -> bf16 Wt[N][K]) ----------------
__global__ __launch_bounds__(256)
void k_transpose_all(const float* __restrict__ w_qkv, const float* __restrict__ w_out,
                     const float* __restrict__ w_fc1, const float* __restrict__ w_fc2,
                     bf16* __restrict__ t_qkv, bf16* __restrict__ t_out,
                     bf16* __restrict__ t_fc1, bf16* __restrict__ t_fc2) {
    __shared__ float tile[32][33];
    int bid = blockIdx.x;
    const float* W; bf16* Wt; int K, N, ti;
    if (bid < 3072)       { W = w_qkv; Wt = t_qkv; K = 1024; N = 3072; ti = bid; }
    else if (bid < 4096)  { W = w_out; Wt = t_out; K = 1024; N = 1024; ti = bid - 3072; }
    else if (bid < 8192)  { W = w_fc1; Wt = t_fc1; K = 1024; N = 4096; ti = bid - 4096; }
    else                  { W = w_fc2; Wt = t_fc2; K = 4096; N = 1024; ti = bid - 8192; }
    int tn = N >> 5;
    int n0 = (ti % tn) * 32, k0 = (ti / tn) * 32;
    int tx = threadIdx.x, ty = threadIdx.y;
#pragma unroll
    for (int i = 0; i < 4; i++)
        tile[ty + i * 8][tx] = W[(size_t)(k0 + ty + i * 8) * N + n0 + tx];
    __syncthreads();
#pragma unroll
    for (int i = 0; i < 4; i++)
        Wt[(size_t)(n0 + ty + i * 8) * K + k0 + tx] = (bf16)tile[tx][ty + i * 8];
}

// ---------------- V transpose + MFMA-k-slot token permutation ----------------
__global__ __launch_bounds__(256)
void k_vtrans(const bf16* __restrict__ qkv, bf16* __restrict__ vT) {
    __shared__ bf16 t[32][33];
    int tok0 = blockIdx.x * 32, f0 = blockIdx.y * 32;
    int tx = threadIdx.x, ty = threadIdx.y;
#pragma unroll
    for (int i = 0; i < 4; i++)
        t[ty + i * 8][tx] = qkv[(size_t)(tok0 + ty + i * 8) * QKVN + 2 * D_MODEL + f0 + tx];
    __syncthreads();
    int s = tx;
    int pp = (s < 16) ? ((s >> 2) * 8 + (s & 3))
                      : (((s - 16) >> 2) * 8 + ((s - 16) & 3) + 4);
#pragma unroll
    for (int i = 0; i < 4; i++)
        vT[(size_t)(f0 + ty + i * 8) * NTOK + tok0 + pp] = t[tx][ty + i * 8];
}

// ---------------- LayerNorm (row = 1024 fp32) -> bf16 ----------------
__global__ __launch_bounds__(256)
void k_layernorm(const float* __restrict__ x, const float* __restrict__ g,
                 const float* __restrict__ b, bf16* __restrict__ out) {
    int row = blockIdx.x;
    int tid = threadIdx.x;
    float4 v = ((const float4*)(x + (size_t)row * D_MODEL))[tid];
    float s  = v.x + v.y + v.z + v.w;
    float ss = v.x * v.x + v.y * v.y + v.z * v.z + v.w * v.w;
#pragma unroll
    for (int off = 32; off > 0; off >>= 1) {
        s  += __shfl_down(s, off, 64);
        ss += __shfl_down(ss, off, 64);
    }
    __shared__ float red[2][4];
    __shared__ float mv[2];
    int wave = tid >> 6, lane = tid & 63;
    if (lane == 0) { red[0][wave] = s; red[1][wave] = ss; }
    __syncthreads();
    if (tid == 0) {
        float S  = red[0][0] + red[0][1] + red[0][2] + red[0][3];
        float SS = red[1][0] + red[1][1] + red[1][2] + red[1][3];
        float mu = S * (1.0f / D_MODEL);
        float var = SS * (1.0f / D_MODEL) - mu * mu;
        mv[0] = mu;
        mv[1] = rsqrtf(var + 1e-5f);
    }
    __syncthreads();
    float mu = mv[0], rs = mv[1];
    float4 gv = ((const float4*)g)[tid];
    float4 bv = ((const float4*)b)[tid];
    bf16x4 ov = { (bf16)((v.x - mu) * rs * gv.x + bv.x),
                  (bf16)((v.y - mu) * rs * gv.y + bv.y),
                  (bf16)((v.z - mu) * rs * gv.z + bv.z),
                  (bf16)((v.w - mu) * rs * gv.w + bv.w) };
    *(bf16x4*)(out + (size_t)row * D_MODEL + tid * 4) = ov;
}

// ---------------- 256x256 8-wave fine-phase MFMA GEMM, depth-3 pipeline (r8-proven) ----------------
template <int DO_GELU>
__global__ __launch_bounds__(512, 2)
void k_gemm256(const bf16* __restrict__ A, const bf16* __restrict__ Bt,
               const float* __restrict__ bias, bf16* __restrict__ outb,
               int M, int N, int K) {
    __shared__ bf16 LA[2][2][8192];   // [dbuf][khalf][256 rows x 32 elems]
    __shared__ bf16 LB[2][2][8192];

    int tid = threadIdx.x;
    int wid = tid >> 6, lane = tid & 63;
    int quad = lane >> 4, l16 = lane & 15;
    int wm = (wid >> 2) * 128;
    int wn = (wid & 3) * 64;

    int nwg = gridDim.x * gridDim.y;
    int bid = blockIdx.y * gridDim.x + blockIdx.x;
    int sid = (bid & 7) * (nwg >> 3) + (bid >> 3);
    int bx = sid % gridDim.x, by = sid / gridDim.x;
    int m0 = by * 256, n0 = bx * 256;

    int l = lane;
    int rsw = l >> 2;
    int csw = 8 * ((l & 3) ^ ((l >> 3) & 3));
    const bf16* pA = A  + (size_t)(m0 + 32 * wid + rsw) * K + csw;
    const bf16* pB = Bt + (size_t)(n0 + 32 * wid + rsw) * K + csw;
    int sbase = wid * 1024;

    int xq = 8 * (quad ^ ((l16 >> 1) & 3));

    f32x4 acc[8][4];
#pragma unroll
    for (int i = 0; i < 8; i++)
#pragma unroll
        for (int j = 0; j < 4; j++) acc[i][j] = (f32x4){0.f, 0.f, 0.f, 0.f};

#define STAGE_A(buf, kh, t) do {                                               \
    gld_lds16(pA + (size_t)(t) * 64 + (kh) * 32,              &LA[buf][kh][sbase]);       \
    gld_lds16(pA + (size_t)16 * K + (size_t)(t) * 64 + (kh) * 32, &LA[buf][kh][sbase + 512]); \
} while (0)
#define STAGE_B(buf, kh, t) do {                                               \
    gld_lds16(pB + (size_t)(t) * 64 + (kh) * 32,              &LB[buf][kh][sbase]);       \
    gld_lds16(pB + (size_t)16 * K + (size_t)(t) * 64 + (kh) * 32, &LB[buf][kh][sbase + 512]); \
} while (0)

    bf16x8 af[4], bfr[4];
#define RD_B(buf, kh)  do {                                                    \
    _Pragma("unroll")                                                          \
    for (int fc = 0; fc < 4; fc++)                                             \
        bfr[fc] = *(const bf16x8*)&LB[buf][kh][(wn + fc * 16 + l16) * 32 + xq];\
} while (0)
#define RD_A(buf, kh, rh) do {                                                 \
    _Pragma("unroll")                                                          \
    for (int fr = 0; fr < 4; fr++)                                             \
        af[fr] = *(const bf16x8*)&LA[buf][kh][(wm + (rh) * 64 + fr * 16 + l16) * 32 + xq]; \
} while (0)
#define MFMA16(rh) do {                                                        \
    __builtin_amdgcn_s_setprio(1);                                             \
    _Pragma("unroll")                                                          \
    for (int fr = 0; fr < 4; fr++)                                             \
        _Pragma("unroll")                                                      \
        for (int fc = 0; fc < 4; fc++)                                         \
            acc[(rh) * 4 + fr][fc] =                                           \
                __builtin_amdgcn_mfma_f32_16x16x32_bf16(af[fr], bfr[fc],       \
                                                        acc[(rh) * 4 + fr][fc], 0, 0, 0); \
    __builtin_amdgcn_s_setprio(0);                                             \
} while (0)

    int nt = K / 64;
    int buf = 0;
    STAGE_A(0, 0, 0); STAGE_B(0, 0, 0);
    STAGE_A(0, 1, 0); STAGE_B(0, 1, 0);
    STAGE_A(1, 0, 1); STAGE_B(1, 0, 1);
    VMW(8); BARRIER();

    for (int t = 0; t < nt - 1; t++) {
        int ts = (t + 2 < nt) ? (t + 2) : (nt - 1);
        RD_B(buf, 0); RD_A(buf, 0, 0);
        STAGE_A(buf ^ 1, 1, t + 1);
        BARRIER(); LGKM0();
        MFMA16(0);
        BARRIER();
        RD_A(buf, 0, 1);
        STAGE_B(buf ^ 1, 1, t + 1);
        BARRIER(); LGKM0();
        MFMA16(1);
        VMW(8); BARRIER();
        RD_B(buf, 1); RD_A(buf, 1, 0);
        STAGE_A(buf, 0, ts);
        BARRIER(); LGKM0();
        MFMA16(0);
        BARRIER();
        RD_A(buf, 1, 1);
        STAGE_B(buf, 0, ts);
        BARRIER(); LGKM0();
        MFMA16(1);
        VMW(8); BARRIER();
        buf ^= 1;
    }
    RD_B(buf, 0); RD_A(buf, 0, 0);
    BARRIER(); LGKM0();
    MFMA16(0);
    BARRIER();
    RD_A(buf, 0, 1);
    BARRIER(); LGKM0();
    MFMA16(1);
    VMW(4); BARRIER();
    RD_B(buf, 1); RD_A(buf, 1, 0);
    BARRIER(); LGKM0();
    MFMA16(0);
    BARRIER();
    RD_A(buf, 1, 1);
    LGKM0();
    MFMA16(1);
    VMW(0);

#undef STAGE_A
#undef STAGE_B
#undef RD_A
#undef RD_B
#undef MFMA16

#pragma unroll
    for (int fi = 0; fi < 8; fi++) {
        int row = m0 + wm + fi * 16 + quad * 4;
#pragma unroll
        for (int fc = 0; fc < 4; fc++) {
            int col = n0 + wn + fc * 16 + l16;
            float bb = bias[col];
#pragma unroll
            for (int r = 0; r < 4; r++) {
                float v = acc[fi][fc][r] + bb;
                if (DO_GELU) v = gelu_fast(v);
                outb[(size_t)(row + r) * N + col] = (bf16)v;
            }
        }
    }
}

// ---------------- 128x128 4-wave fine-phase MFMA GEMM, depth-3, plain fp32 epilogue ----------------
// C[M][N] = A[M][K] @ Bt[N][K]^T + bias + res, fp32 out (no atomics, no split-K).
// Grid (N/128, M/128) = 256 blocks for both users -> 1 block/CU.
// 256 thr = 4 waves (2M x 2N), per-wave 64x64 = acc[4][4]: 16 MFMA per 8 ds_read_b128
// (0.5 reads/MFMA vs 0.75 at 128x64) and 1 block/CU -> per-CU LDS-pipe traffic ~40%
// lower than the r10 128x64 config (FC2's measured wall was LDS bandwidth).
// res may ALIAS outf (FC2: out += ...), so res/outf are NOT __restrict__.
// LDS = 2dbuf x 2kh x (A 8KB + B 8KB) = 64 KB.
// Depth-3 ledger (stage-groups of 4: A2+B2, FIFO per wave):
//   entry: 8 in flight = [S(t,kh1):4][S(t+1,kh0):4]
//   phase kh0: RD(kh0); STAGE S(t+1,kh1)->buf^1 (12) | bar lgkm0 MFMA16 VMW(8) bar -> S(t,kh1) landed
//   phase kh1: RD(kh1); STAGE S(t+2,kh0)->buf   (12) | bar lgkm0 MFMA16 VMW(8) bar -> S(t+1,kh0) landed
//     (WAR-safe: buf.kh0 readers finished at phase-kh0's closing barrier)
//   tail staging clamped to nt-1 (dummy lands in wrong-parity buf.kh0, never read);
//   final tile: VMW(4) (S(last,kh1) is older than the 4 dummies) then VMW(0).
__global__ __launch_bounds__(256, 2)
void k_gemm128sq(const bf16* __restrict__ A, const bf16* __restrict__ Bt,
                 const float* __restrict__ bias, const float* res,
                 float* outf, int M, int N, int K) {
    __shared__ bf16 LA[2][2][4096];   // [dbuf][kh][128 rows x 32 elems] = 8KB each
    __shared__ bf16 LB[2][2][4096];

    int tid = threadIdx.x;
    int wid = tid >> 6, lane = tid & 63;
    int quad = lane >> 4, l16 = lane & 15;
    int wm = (wid >> 1) * 64;
    int wn = (wid & 1) * 64;

    int nwg = gridDim.x * gridDim.y;
    int bid = blockIdx.y * gridDim.x + blockIdx.x;
    int sid = (bid & 7) * (nwg >> 3) + (bid >> 3);
    int bx = sid % gridDim.x, by = sid / gridDim.x;
    int m0 = by * 128, n0 = bx * 128;

    int l = lane;
    int rsw = l >> 2;
    int csw = 8 * ((l & 3) ^ ((l >> 3) & 3));
    const bf16* pA = A  + (size_t)(m0 + 32 * wid + rsw) * K + csw;
    const bf16* pB = Bt + (size_t)(n0 + 32 * wid + rsw) * K + csw;
    int sbase = wid * 1024;           // 4 waves x (2 chunks x 512 elems)

    int xq = 8 * (quad ^ ((l16 >> 1) & 3));

    f32x4 acc[4][4];
#pragma unroll
    for (int i = 0; i < 4; i++)
#pragma unroll
        for (int j = 0; j < 4; j++) acc[i][j] = (f32x4){0.f, 0.f, 0.f, 0.f};

#define STAGE4(buf, kh, t) do {                                                \
    gld_lds16(pA + (size_t)(t) * 64 + (kh) * 32,                  &LA[buf][kh][sbase]);       \
    gld_lds16(pA + (size_t)16 * K + (size_t)(t) * 64 + (kh) * 32, &LA[buf][kh][sbase + 512]); \
    gld_lds16(pB + (size_t)(t) * 64 + (kh) * 32,                  &LB[buf][kh][sbase]);       \
    gld_lds16(pB + (size_t)16 * K + (size_t)(t) * 64 + (kh) * 32, &LB[buf][kh][sbase + 512]); \
} while (0)

    bf16x8 af[4], bfr[4];
#define RD(buf, kh)  do {                                                      \
    _Pragma("unroll")                                                          \
    for (int fc = 0; fc < 4; fc++)                                             \
        bfr[fc] = *(const bf16x8*)&LB[buf][kh][(wn + fc * 16 + l16) * 32 + xq];\
    _Pragma("unroll")                                                          \
    for (int fr = 0; fr < 4; fr++)                                             \
        af[fr] = *(const bf16x8*)&LA[buf][kh][(wm + fr * 16 + l16) * 32 + xq]; \
} while (0)
#define MFMA16() do {                                                          \
    __builtin_amdgcn_s_setprio(1);                                             \
    _Pragma("unroll")                                                          \
    for (int fr = 0; fr < 4; fr++)                                             \
        _Pragma("unroll")                                                      \
        for (int fc = 0; fc < 4; fc++)                                         \
            acc[fr][fc] =                                                      \
                __builtin_amdgcn_mfma_f32_16x16x32_bf16(af[fr], bfr[fc],       \
                                                        acc[fr][fc], 0, 0, 0); \
    __builtin_amdgcn_s_setprio(0);                                             \
} while (0)

    int nt = K / 64;                  // out-proj 16, FC2 64 (both >= 3)
    int buf = 0;
    // prologue: S(0,kh0), S(0,kh1), S(1,kh0) -> 12 in flight
    STAGE4(0, 0, 0);
    STAGE4(0, 1, 0);
    STAGE4(1, 0, 1);
    VMW(8); BARRIER();                // S(0,kh0) landed; 8 in flight

    for (int t = 0; t < nt - 1; t++) {
        int ts = (t + 2 < nt) ? (t + 2) : (nt - 1);
        // phase kh0
        RD(buf, 0);
        STAGE4(buf ^ 1, 1, t + 1);    // S(t+1,kh1) -> 12
        BARRIER(); LGKM0();
        MFMA16();
        VMW(8); BARRIER();            // S(t,kh1) landed
        // phase kh1
        RD(buf, 1);
        STAGE4(buf, 0, ts);           // S(t+2,kh0) -> 12 (WAR-safe; tail = dummy)
        BARRIER(); LGKM0();
        MFMA16();
        VMW(8); BARRIER();            // S(t+1,kh0) landed
        buf ^= 1;
    }
    // tile nt-1: entry 8 = [S(last,kh1):4][dummy:4]
    RD(buf, 0);
    BARRIER(); LGKM0();
    MFMA16();
    VMW(4); BARRIER();                // S(last,kh1) landed (4 dummies remain)
    RD(buf, 1);
    LGKM0();
    MFMA16();
    VMW(0);                           // drain dummies before LDS teardown

#undef STAGE4
#undef RD
#undef MFMA16

#pragma unroll
    for (int fr = 0; fr < 4; fr++) {
        int row = m0 + wm + fr * 16 + quad * 4;
#pragma unroll
        for (int fc = 0; fc < 4; fc++) {
            int col = n0 + wn + fc * 16 + l16;
            float bb = bias[col];
#pragma unroll
            for (int r = 0; r < 4; r++) {
                size_t idx = (size_t)(row + r) * N + col;
                outf[idx] = res[idx] + acc[fr][fc][r] + bb;
            }
        }
    }
}

// ---------------- attention: counted-vmcnt pipeline (r11; K 3-buf depth-2, V 2-buf) ----------------
__global__ __launch_bounds__(256)
void k_attention2(const bf16* __restrict__ qkv, const bf16* __restrict__ vT,
                  bf16* __restrict__ o) {
    __shared__ bf16 Ks[3][2][64][32];   // [buf][hd-chunk][kv][32elem]
    __shared__ bf16 Vs[2][2][64][32];   // [buf][kv-pair tp][hd][32 perm-tok]

    int tid = threadIdx.x, wave = tid >> 6, lane = tid & 63;
    int quad = lane >> 4, l16 = lane & 15;
    int bh = blockIdx.y;
    int b = bh >> 4, h = bh & 15;
    int q0 = blockIdx.x * 64 + wave * 16;

    const bf16* Qb  = qkv + (size_t)b * SEQ * QKVN + h * HDIM;
    const bf16* Kb  = Qb + D_MODEL;
    const bf16* vTb = vT + (size_t)h * HDIM * NTOK + b * SEQ;

    const float QSCALE = 0.125f * 1.44269504089f;
    bf16x8 qf[2];
#pragma unroll
    for (int c = 0; c < 2; c++) {
        bf16x8 qraw = *(const bf16x8*)(Qb + (size_t)(q0 + l16) * QKVN + c * 32 + quad * 8);
#pragma unroll
        for (int i = 0; i < 8; i++) qf[c][i] = (bf16)((float)qraw[i] * QSCALE);
    }

    const bf16* gK0 = Kb + (size_t)(wave * 16 + (lane >> 2)) * QKVN + (lane & 3) * 8;
    const bf16* gK1 = gK0 + 32;
    const bf16* gV0 = vTb + (size_t)(wave * 16 + (lane >> 2)) * NTOK + (lane & 3) * 8;
    const bf16* gV1 = gV0 + 32;

#define STAGE_K(b3, t) do {                                                    \
    size_t koff_ = (size_t)(t) * 64 * QKVN;                                    \
    gld_lds16(gK0 + koff_, &Ks[b3][0][wave * 16][0]);                          \
    gld_lds16(gK1 + koff_, &Ks[b3][1][wave * 16][0]);                          \
} while (0)
#define STAGE_V(b2, t) do {                                                    \
    gld_lds16(gV0 + (t) * 64, &Vs[b2][0][wave * 16][0]);                       \
    gld_lds16(gV1 + (t) * 64, &Vs[b2][1][wave * 16][0]);                       \
} while (0)

    f32x4 oacc[4];
#pragma unroll
    for (int i = 0; i < 4; i++) oacc[i] = (f32x4){0.f, 0.f, 0.f, 0.f};
    float lsum = 0.f;

    const int NT = SEQ / 64;          // 32
    STAGE_K(0, 0);
    STAGE_K(1, 1);
    STAGE_V(0, 0);
    VMW(4); BARRIER();                // K(0) landed; K(1):2 + V(0):2 in flight

    int b3 = 0, b2 = 0;
    for (int t = 0; t < NT; t++) {
        if (t + 2 < NT) STAGE_K((t + 2) % 3, t + 2);
        if (t + 1 < NT) STAGE_V((t + 1) & 1, t + 1);

        f32x4 s[4];
        __builtin_amdgcn_s_setprio(1);
#pragma unroll
        for (int tt = 0; tt < 4; tt++) {
            bf16x8 af0 = *(const bf16x8*)(&Ks[b3][0][tt * 16 + l16][quad * 8]);
            bf16x8 af1 = *(const bf16x8*)(&Ks[b3][1][tt * 16 + l16][quad * 8]);
            f32x4 z = (f32x4){0.f, 0.f, 0.f, 0.f};
            z = __builtin_amdgcn_mfma_f32_16x16x32_bf16(af0, qf[0], z, 0, 0, 0);
            z = __builtin_amdgcn_mfma_f32_16x16x32_bf16(af1, qf[1], z, 0, 0, 0);
            s[tt] = z;
        }
        __builtin_amdgcn_s_setprio(0);

        if (t + 2 < NT)      { VMW(4); }
        else if (t + 1 < NT) { VMW(2); }
        else                 { VMW(0); }
        BARRIER();

        bf16x4 p[4];
#pragma unroll
        for (int tt = 0; tt < 4; tt++)
#pragma unroll
            for (int r = 0; r < 4; r++) {
                float pf = fast_exp2(s[tt][r]);
                lsum += pf;
                p[tt][r] = (bf16)pf;
            }

        __builtin_amdgcn_s_setprio(1);
#pragma unroll
        for (int tp = 0; tp < 2; tp++) {
            bf16x8 pa = __builtin_shufflevector(p[2 * tp], p[2 * tp + 1], 0, 1, 2, 3, 4, 5, 6, 7);
#pragma unroll
            for (int nt = 0; nt < 4; nt++) {
                bf16x8 vb = *(const bf16x8*)(&Vs[b2][tp][nt * 16 + l16][quad * 8]);
                oacc[nt] = __builtin_amdgcn_mfma_f32_16x16x32_bf16(pa, vb, oacc[nt], 0, 0, 0);
            }
        }
        __builtin_amdgcn_s_setprio(0);

        BARRIER();
        b3 = (b3 + 1) % 3;
        b2 ^= 1;
    }

#undef STAGE_K
#undef STAGE_V

    lsum += __shfl_xor(lsum, 16, 64);
    lsum += __shfl_xor(lsum, 32, 64);
    float invl[4];
#pragma unroll
    for (int r = 0; r < 4; r++)
        invl[r] = 1.0f / __shfl(lsum, quad * 4 + r, 16);

#pragma unroll
    for (int nt = 0; nt < 4; nt++)
#pragma unroll
        for (int r = 0; r < 4; r++)
            o[(size_t)(b * SEQ + q0 + quad * 4 + r) * D_MODEL + h * HDIM + nt * 16 + l16] =
                (bf16)(oacc[nt][r] * invl[r]);
}

// ---------------- launcher ----------------
extern "C" void kernel_launch(void* const* d_in, const int* in_sizes, int n_in,
                              void* d_out, int out_size, void* d_ws, size_t ws_size,
                              hipStream_t stream) {
    const float* x     = (const float*)d_in[0];
    const float* ln1_g = (const float*)d_in[1];
    const float* ln1_b = (const float*)d_in[2];
    const float* w_qkv = (const float*)d_in[3];
    const float* b_qkv = (const float*)d_in[4];
    const float* w_out = (const float*)d_in[5];
    const float* b_out = (const float*)d_in[6];
    const float* ln2_g = (const float*)d_in[7];
    const float* ln2_b = (const float*)d_in[8];
    const float* w_fc1 = (const float*)d_in[9];
    const float* b_fc1 = (const float*)d_in[10];
    const float* w_fc2 = (const float*)d_in[11];
    const float* b_fc2 = (const float*)d_in[12];
    float* out = (float*)d_out;

    uintptr_t ws = (uintptr_t)d_ws;
    bf16* wt_qkv = (bf16*)(ws + 0);                  //  6291456 B
    bf16* wt_out = (bf16*)(ws + 6291456);            //  2097152 B
    bf16* wt_fc1 = (bf16*)(ws + 8388608);            //  8388608 B
    bf16* wt_fc2 = (bf16*)(ws + 16777216);           //  8388608 B
    bf16* hbuf   = (bf16*)(ws + 25165824);           //  8388608 B
    bf16* vT     = hbuf;
    bf16* qkv    = (bf16*)(ws + 33554432);           // 25165824 B
    bf16* attn_o = (bf16*)(ws + 58720256);           //  8388608 B
    bf16* hgelu  = (bf16*)(ws + 33554432);           // 33554432 B (overlays dead qkv+attn_o)

    k_transpose_all<<<12288, dim3(32, 8), 0, stream>>>(w_qkv, w_out, w_fc1, w_fc2,
                                                       wt_qkv, wt_out, wt_fc1, wt_fc2);

    k_layernorm<<<NTOK, 256, 0, stream>>>(x, ln1_g, ln1_b, hbuf);

    // QKV: 256^2 fine-phase depth-3 kernel, grid 12x16 = 192 blocks
    k_gemm256<0><<<dim3(QKVN / 256, NTOK / 256), 512, 0, stream>>>(
        hbuf, wt_qkv, b_qkv, qkv, NTOK, QKVN, D_MODEL);

    k_vtrans<<<dim3(NTOK / 32, D_MODEL / 32), dim3(32, 8), 0, stream>>>(qkv, vT);

    k_attention2<<<dim3(SEQ / 64, BATCH * NHEAD), 256, 0, stream>>>(qkv, vT, attn_o);

    // out-proj: 128x128 fine-phase depth-3, grid 8x32 = 256 blocks; out = attn_o@W + b + x
    k_gemm128sq<<<dim3(D_MODEL / 128, NTOK / 128), 256, 0, stream>>>(
        attn_o, wt_out, b_out, x, out, NTOK, D_MODEL, D_MODEL);

    k_layernorm<<<NTOK, 256, 0, stream>>>(out, ln2_g, ln2_b, hbuf);

    // FC1: 256^2 fine-phase depth-3 kernel + fast GELU, grid 16x16 = 256 blocks
    k_gemm256<1><<<dim3(FFDIM / 256, NTOK / 256), 512, 0, stream>>>(
        hbuf, wt_fc1, b_fc1, hgelu, NTOK, FFDIM, D_MODEL);

    // FC2: 128x128 fine-phase depth-3, grid 8x32 = 256 blocks, K=4096 (nt=64);
    // out += hgelu@W + b (res aliases out; unique writes, no atomics, no split-K)
    k_gemm128sq<<<dim3(D_MODEL / 128, NTOK / 128), 256, 0, stream>>>(
        hgelu, wt_fc2, b_fc2, out, out, NTOK, D_MODEL, FFDIM);
}

// Round 13
// 345.592 us; speedup vs baseline: 1.0514x; 1.0514x over previous
//
#include <hip/hip_runtime.h>
#include <stdint.h>
#include <math.h>

#define D_MODEL 1024
#define NHEAD   16
#define HDIM    64
#define FFDIM   4096
#define SEQ     2048
#define BATCH   2
#define NTOK    (BATCH*SEQ)
#define QKVN    (3*D_MODEL)

typedef __bf16 bf16;
typedef __attribute__((ext_vector_type(8))) __bf16 bf16x8;
typedef __attribute__((ext_vector_type(4))) __bf16 bf16x4;
typedef __attribute__((ext_vector_type(4))) float f32x4;

__device__ __forceinline__ void gld_lds16(const void* g, void* l) {
    __builtin_amdgcn_global_load_lds((__attribute__((address_space(1))) void*)g,
                                     (__attribute__((address_space(3))) void*)l,
                                     16, 0, 0);
}

__device__ __forceinline__ float fast_exp2(float x) {
#if __has_builtin(__builtin_amdgcn_exp2f)
    return __builtin_amdgcn_exp2f(x);
#else
    return __expf(x * 0.69314718056f);
#endif
}

__device__ __forceinline__ float fast_rcp(float x) {
#if __has_builtin(__builtin_amdgcn_rcpf)
    return __builtin_amdgcn_rcpf(x);
#else
    return 1.0f / x;
#endif
}

// tanh-form GELU: max |err vs erf-gelu| ~3e-4, below bf16 output quantization.
__device__ __forceinline__ float gelu_fast(float x) {
    float xx = x * x;
    float y  = x * fmaf(0.035677408137f, xx, 0.7978845608f);
    float z  = fminf(-2.8853900817779268f * y, 126.0f);
    float e  = fast_exp2(z);
    return x * fast_rcp(1.0f + e);
}

#define BARRIER() do {                                         \
    __builtin_amdgcn_s_barrier();                              \
    asm volatile("" ::: "memory");                             \
} while (0)
#define LGKM0() asm volatile("s_waitcnt lgkmcnt(0)" ::: "memory")
#define VMW(N)  asm volatile("s_waitcnt vmcnt(" #N ")" ::: "memory")

// ---------------- all 4 weight transposes (fp32 W[K][N] -> bf16 Wt[N][K]) ----------------
__global__ __launch_bounds__(256)
void k_transpose_all(const float* __restrict__ w_qkv, const float* __restrict__ w_out,
                     const float* __restrict__ w_fc1, const float* __restrict__ w_fc2,
                     bf16* __restrict__ t_qkv, bf16* __restrict__ t_out,
                     bf16* __restrict__ t_fc1, bf16* __restrict__ t_fc2) {
    __shared__ float tile[32][33];
    int bid = blockIdx.x;
    const float* W; bf16* Wt; int K, N, ti;
    if (bid < 3072)       { W = w_qkv; Wt = t_qkv; K = 1024; N = 3072; ti = bid; }
    else if (bid < 4096)  { W = w_out; Wt = t_out; K = 1024; N = 1024; ti = bid - 3072; }
    else if (bid < 8192)  { W = w_fc1; Wt = t_fc1; K = 1024; N = 4096; ti = bid - 4096; }
    else                  { W = w_fc2; Wt = t_fc2; K = 4096; N = 1024; ti = bid - 8192; }
    int tn = N >> 5;
    int n0 = (ti % tn) * 32, k0 = (ti / tn) * 32;
    int tx = threadIdx.x, ty = threadIdx.y;
#pragma unroll
    for (int i = 0; i < 4; i++)
        tile[ty + i * 8][tx] = W[(size_t)(k0 + ty + i * 8) * N + n0 + tx];
    __syncthreads();
#pragma unroll
    for (int i = 0; i < 4; i++)
        Wt[(size_t)(n0 + ty + i * 8) * K + k0 + tx] = (bf16)tile[tx][ty + i * 8];
}

// ---------------- V transpose + MFMA-k-slot token permutation ----------------
__global__ __launch_bounds__(256)
void k_vtrans(const bf16* __restrict__ qkv, bf16* __restrict__ vT) {
    __shared__ bf16 t[32][33];
    int tok0 = blockIdx.x * 32, f0 = blockIdx.y * 32;
    int tx = threadIdx.x, ty = threadIdx.y;
#pragma unroll
    for (int i = 0; i < 4; i++)
        t[ty + i * 8][tx] = qkv[(size_t)(tok0 + ty + i * 8) * QKVN + 2 * D_MODEL + f0 + tx];
    __syncthreads();
    int s = tx;
    int pp = (s < 16) ? ((s >> 2) * 8 + (s & 3))
                      : (((s - 16) >> 2) * 8 + ((s - 16) & 3) + 4);
#pragma unroll
    for (int i = 0; i < 4; i++)
        vT[(size_t)(f0 + ty + i * 8) * NTOK + tok0 + pp] = t[tx][ty + i * 8];
}

// ---------------- LayerNorm (row = 1024 fp32) -> bf16 ----------------
__global__ __launch_bounds__(256)
void k_layernorm(const float* __restrict__ x, const float* __restrict__ g,
                 const float* __restrict__ b, bf16* __restrict__ out) {
    int row = blockIdx.x;
    int tid = threadIdx.x;
    float4 v = ((const float4*)(x + (size_t)row * D_MODEL))[tid];
    float s  = v.x + v.y + v.z + v.w;
    float ss = v.x * v.x + v.y * v.y + v.z * v.z + v.w * v.w;
#pragma unroll
    for (int off = 32; off > 0; off >>= 1) {
        s  += __shfl_down(s, off, 64);
        ss += __shfl_down(ss, off, 64);
    }
    __shared__ float red[2][4];
    __shared__ float mv[2];
    int wave = tid >> 6, lane = tid & 63;
    if (lane == 0) { red[0][wave] = s; red[1][wave] = ss; }
    __syncthreads();
    if (tid == 0) {
        float S  = red[0][0] + red[0][1] + red[0][2] + red[0][3];
        float SS = red[1][0] + red[1][1] + red[1][2] + red[1][3];
        float mu = S * (1.0f / D_MODEL);
        float var = SS * (1.0f / D_MODEL) - mu * mu;
        mv[0] = mu;
        mv[1] = rsqrtf(var + 1e-5f);
    }
    __syncthreads();
    float mu = mv[0], rs = mv[1];
    float4 gv = ((const float4*)g)[tid];
    float4 bv = ((const float4*)b)[tid];
    bf16x4 ov = { (bf16)((v.x - mu) * rs * gv.x + bv.x),
                  (bf16)((v.y - mu) * rs * gv.y + bv.y),
                  (bf16)((v.z - mu) * rs * gv.z + bv.z),
                  (bf16)((v.w - mu) * rs * gv.w + bv.w) };
    *(bf16x4*)(out + (size_t)row * D_MODEL + tid * 4) = ov;
}

// ---------------- 256x256 8-wave fine-phase MFMA GEMM, depth-3, thinned barriers ----------------
// r13 change vs r8: the two MID-phase barriers per K-tile are removed (8 -> 4 barriers).
// Correctness audit: WAR is carried by each phase's CLOSING VMW+BARRIER — every wave's
// ds_reads of a buffer complete (LGKM0 before its MFMAs) before that barrier, and all
// staging into that buffer is issued only after it. Mid-phase RD_A(rh1) reads the SAME
// still-valid buffer, so no sync is needed between the two MFMA16 clusters.
template <int DO_GELU>
__global__ __launch_bounds__(512, 2)
void k_gemm256(const bf16* __restrict__ A, const bf16* __restrict__ Bt,
               const float* __restrict__ bias, bf16* __restrict__ outb,
               int M, int N, int K) {
    __shared__ bf16 LA[2][2][8192];   // [dbuf][khalf][256 rows x 32 elems]
    __shared__ bf16 LB[2][2][8192];

    int tid = threadIdx.x;
    int wid = tid >> 6, lane = tid & 63;
    int quad = lane >> 4, l16 = lane & 15;
    int wm = (wid >> 2) * 128;
    int wn = (wid & 3) * 64;

    int nwg = gridDim.x * gridDim.y;
    int bid = blockIdx.y * gridDim.x + blockIdx.x;
    int sid = (bid & 7) * (nwg >> 3) + (bid >> 3);
    int bx = sid % gridDim.x, by = sid / gridDim.x;
    int m0 = by * 256, n0 = bx * 256;

    int l = lane;
    int rsw = l >> 2;
    int csw = 8 * ((l & 3) ^ ((l >> 3) & 3));
    const bf16* pA = A  + (size_t)(m0 + 32 * wid + rsw) * K + csw;
    const bf16* pB = Bt + (size_t)(n0 + 32 * wid + rsw) * K + csw;
    int sbase = wid * 1024;

    int xq = 8 * (quad ^ ((l16 >> 1) & 3));

    f32x4 acc[8][4];
#pragma unroll
    for (int i = 0; i < 8; i++)
#pragma unroll
        for (int j = 0; j < 4; j++) acc[i][j] = (f32x4){0.f, 0.f, 0.f, 0.f};

#define STAGE_A(buf, kh, t) do {                                               \
    gld_lds16(pA + (size_t)(t) * 64 + (kh) * 32,              &LA[buf][kh][sbase]);       \
    gld_lds16(pA + (size_t)16 * K + (size_t)(t) * 64 + (kh) * 32, &LA[buf][kh][sbase + 512]); \
} while (0)
#define STAGE_B(buf, kh, t) do {                                               \
    gld_lds16(pB + (size_t)(t) * 64 + (kh) * 32,              &LB[buf][kh][sbase]);       \
    gld_lds16(pB + (size_t)16 * K + (size_t)(t) * 64 + (kh) * 32, &LB[buf][kh][sbase + 512]); \
} while (0)

    bf16x8 af[4], bfr[4];
#define RD_B(buf, kh)  do {                                                    \
    _Pragma("unroll")                                                          \
    for (int fc = 0; fc < 4; fc++)                                             \
        bfr[fc] = *(const bf16x8*)&LB[buf][kh][(wn + fc * 16 + l16) * 32 + xq];\
} while (0)
#define RD_A(buf, kh, rh) do {                                                 \
    _Pragma("unroll")                                                          \
    for (int fr = 0; fr < 4; fr++)                                             \
        af[fr] = *(const bf16x8*)&LA[buf][kh][(wm + (rh) * 64 + fr * 16 + l16) * 32 + xq]; \
} while (0)
#define MFMA16(rh) do {                                                        \
    __builtin_amdgcn_s_setprio(1);                                             \
    _Pragma("unroll")                                                          \
    for (int fr = 0; fr < 4; fr++)                                             \
        _Pragma("unroll")                                                      \
        for (int fc = 0; fc < 4; fc++)                                         \
            acc[(rh) * 4 + fr][fc] =                                           \
                __builtin_amdgcn_mfma_f32_16x16x32_bf16(af[fr], bfr[fc],       \
                                                        acc[(rh) * 4 + fr][fc], 0, 0, 0); \
    __builtin_amdgcn_s_setprio(0);                                             \
} while (0)

    int nt = K / 64;
    int buf = 0;
    STAGE_A(0, 0, 0); STAGE_B(0, 0, 0);
    STAGE_A(0, 1, 0); STAGE_B(0, 1, 0);
    STAGE_A(1, 0, 1); STAGE_B(1, 0, 1);
    VMW(8); BARRIER();                 // S(0,kh0) landed; 8 in flight

    for (int t = 0; t < nt - 1; t++) {
        int ts = (t + 2 < nt) ? (t + 2) : (nt - 1);
        // phase kh0: one barrier-pair, 32 MFMA
        RD_B(buf, 0); RD_A(buf, 0, 0);
        STAGE_A(buf ^ 1, 1, t + 1);
        BARRIER(); LGKM0();
        MFMA16(0);
        RD_A(buf, 0, 1);               // same buffer, no barrier needed
        STAGE_B(buf ^ 1, 1, t + 1);
        LGKM0();
        MFMA16(1);
        VMW(8); BARRIER();             // S(t,kh1) landed
        // phase kh1
        RD_B(buf, 1); RD_A(buf, 1, 0);
        STAGE_A(buf, 0, ts);
        BARRIER(); LGKM0();
        MFMA16(0);
        RD_A(buf, 1, 1);
        STAGE_B(buf, 0, ts);
        LGKM0();
        MFMA16(1);
        VMW(8); BARRIER();             // S(t+1,kh0) landed
        buf ^= 1;
    }
    // tile nt-1: entry 8 = [S(last,kh1):4][dummy:4]
    RD_B(buf, 0); RD_A(buf, 0, 0);
    BARRIER(); LGKM0();
    MFMA16(0);
    RD_A(buf, 0, 1);
    LGKM0();
    MFMA16(1);
    VMW(4); BARRIER();                 // S(last,kh1) landed (4 dummies remain)
    RD_B(buf, 1); RD_A(buf, 1, 0);
    LGKM0();
    MFMA16(0);
    RD_A(buf, 1, 1);
    LGKM0();
    MFMA16(1);
    VMW(0);                            // drain dummies before LDS teardown

#undef STAGE_A
#undef STAGE_B
#undef RD_A
#undef RD_B
#undef MFMA16

#pragma unroll
    for (int fi = 0; fi < 8; fi++) {
        int row = m0 + wm + fi * 16 + quad * 4;
#pragma unroll
        for (int fc = 0; fc < 4; fc++) {
            int col = n0 + wn + fc * 16 + l16;
            float bb = bias[col];
#pragma unroll
            for (int r = 0; r < 4; r++) {
                float v = acc[fi][fc][r] + bb;
                if (DO_GELU) v = gelu_fast(v);
                outb[(size_t)(row + r) * N + col] = (bf16)v;
            }
        }
    }
}

// ---------------- 128x64 4-wave fine-phase MFMA GEMM, depth-3, plain fp32 epilogue (r10-proven) ----------------
__global__ __launch_bounds__(256, 3)
void k_gemm128x64(const bf16* __restrict__ A, const bf16* __restrict__ Bt,
                  const float* __restrict__ bias, const float* res,
                  float* outf, int M, int N, int K) {
    __shared__ bf16 LA[2][2][4096];   // [dbuf][kh][128 rows x 32 elems] = 8KB each
    __shared__ bf16 LB[2][2][2048];   // [dbuf][kh][ 64 rows x 32 elems] = 4KB each

    int tid = threadIdx.x;
    int wid = tid >> 6, lane = tid & 63;
    int quad = lane >> 4, l16 = lane & 15;
    int wm = (wid >> 1) * 64;
    int wn = (wid & 1) * 32;

    int nwg = gridDim.x * gridDim.y;
    int bid = blockIdx.y * gridDim.x + blockIdx.x;
    int sid = (bid & 7) * (nwg >> 3) + (bid >> 3);
    int bx = sid % gridDim.x, by = sid / gridDim.x;
    int m0 = by * 128, n0 = bx * 64;

    int l = lane;
    int rsw = l >> 2;
    int csw = 8 * ((l & 3) ^ ((l >> 3) & 3));
    const bf16* pA = A  + (size_t)(m0 + 32 * wid + rsw) * K + csw;
    const bf16* pB = Bt + (size_t)(n0 + 16 * wid + rsw) * K + csw;
    int sbaseA = wid * 1024;
    int sbaseB = wid * 512;

    int xq = 8 * (quad ^ ((l16 >> 1) & 3));

    f32x4 acc[4][2];
#pragma unroll
    for (int i = 0; i < 4; i++)
#pragma unroll
        for (int j = 0; j < 2; j++) acc[i][j] = (f32x4){0.f, 0.f, 0.f, 0.f};

#define STAGE_AB(buf, kh, t) do {                                              \
    gld_lds16(pA + (size_t)(t) * 64 + (kh) * 32,                  &LA[buf][kh][sbaseA]);       \
    gld_lds16(pA + (size_t)16 * K + (size_t)(t) * 64 + (kh) * 32, &LA[buf][kh][sbaseA + 512]); \
    gld_lds16(pB + (size_t)(t) * 64 + (kh) * 32,                  &LB[buf][kh][sbaseB]);       \
} while (0)

    bf16x8 af[4], bfr[2];
#define RD(buf, kh)  do {                                                      \
    _Pragma("unroll")                                                          \
    for (int fc = 0; fc < 2; fc++)                                             \
        bfr[fc] = *(const bf16x8*)&LB[buf][kh][(wn + fc * 16 + l16) * 32 + xq];\
    _Pragma("unroll")                                                          \
    for (int fr = 0; fr < 4; fr++)                                             \
        af[fr] = *(const bf16x8*)&LA[buf][kh][(wm + fr * 16 + l16) * 32 + xq]; \
} while (0)
#define MFMA8() do {                                                           \
    __builtin_amdgcn_s_setprio(1);                                             \
    _Pragma("unroll")                                                          \
    for (int fr = 0; fr < 4; fr++)                                             \
        _Pragma("unroll")                                                      \
        for (int fc = 0; fc < 2; fc++)                                         \
            acc[fr][fc] =                                                      \
                __builtin_amdgcn_mfma_f32_16x16x32_bf16(af[fr], bfr[fc],       \
                                                        acc[fr][fc], 0, 0, 0); \
    __builtin_amdgcn_s_setprio(0);                                             \
} while (0)

    int nt = K / 64;
    int buf = 0;
    STAGE_AB(0, 0, 0);
    STAGE_AB(0, 1, 0);
    STAGE_AB(1, 0, 1);
    VMW(6); BARRIER();

    for (int t = 0; t < nt - 1; t++) {
        int ts = (t + 2 < nt) ? (t + 2) : (nt - 1);
        RD(buf, 0);
        STAGE_AB(buf ^ 1, 1, t + 1);
        BARRIER(); LGKM0();
        MFMA8();
        VMW(6); BARRIER();
        RD(buf, 1);
        STAGE_AB(buf, 0, ts);
        BARRIER(); LGKM0();
        MFMA8();
        VMW(6); BARRIER();
        buf ^= 1;
    }
    RD(buf, 0);
    BARRIER(); LGKM0();
    MFMA8();
    VMW(3); BARRIER();
    RD(buf, 1);
    LGKM0();
    MFMA8();
    VMW(0);

#undef STAGE_AB
#undef RD
#undef MFMA8

#pragma unroll
    for (int fr = 0; fr < 4; fr++) {
        int row = m0 + wm + fr * 16 + quad * 4;
#pragma unroll
        for (int fc = 0; fc < 2; fc++) {
            int col = n0 + wn + fc * 16 + l16;
            float bb = bias[col];
#pragma unroll
            for (int r = 0; r < 4; r++) {
                size_t idx = (size_t)(row + r) * N + col;
                outf[idx] = res[idx] + acc[fr][fc][r] + bb;
            }
        }
    }
}

// ---------------- attention: counted-vmcnt pipeline (r11; K 3-buf depth-2, V 2-buf) ----------------
__global__ __launch_bounds__(256)
void k_attention2(const bf16* __restrict__ qkv, const bf16* __restrict__ vT,
                  bf16* __restrict__ o) {
    __shared__ bf16 Ks[3][2][64][32];   // [buf][hd-chunk][kv][32elem]
    __shared__ bf16 Vs[2][2][64][32];   // [buf][kv-pair tp][hd][32 perm-tok]

    int tid = threadIdx.x, wave = tid >> 6, lane = tid & 63;
    int quad = lane >> 4, l16 = lane & 15;
    int bh = blockIdx.y;
    int b = bh >> 4, h = bh & 15;
    int q0 = blockIdx.x * 64 + wave * 16;

    const bf16* Qb  = qkv + (size_t)b * SEQ * QKVN + h * HDIM;
    const bf16* Kb  = Qb + D_MODEL;
    const bf16* vTb = vT + (size_t)h * HDIM * NTOK + b * SEQ;

    const float QSCALE = 0.125f * 1.44269504089f;
    bf16x8 qf[2];
#pragma unroll
    for (int c = 0; c < 2; c++) {
        bf16x8 qraw = *(const bf16x8*)(Qb + (size_t)(q0 + l16) * QKVN + c * 32 + quad * 8);
#pragma unroll
        for (int i = 0; i < 8; i++) qf[c][i] = (bf16)((float)qraw[i] * QSCALE);
    }

    const bf16* gK0 = Kb + (size_t)(wave * 16 + (lane >> 2)) * QKVN + (lane & 3) * 8;
    const bf16* gK1 = gK0 + 32;
    const bf16* gV0 = vTb + (size_t)(wave * 16 + (lane >> 2)) * NTOK + (lane & 3) * 8;
    const bf16* gV1 = gV0 + 32;

#define STAGE_K(b3, t) do {                                                    \
    size_t koff_ = (size_t)(t) * 64 * QKVN;                                    \
    gld_lds16(gK0 + koff_, &Ks[b3][0][wave * 16][0]);                          \
    gld_lds16(gK1 + koff_, &Ks[b3][1][wave * 16][0]);                          \
} while (0)
#define STAGE_V(b2, t) do {                                                    \
    gld_lds16(gV0 + (t) * 64, &Vs[b2][0][wave * 16][0]);                       \
    gld_lds16(gV1 + (t) * 64, &Vs[b2][1][wave * 16][0]);                       \
} while (0)

    f32x4 oacc[4];
#pragma unroll
    for (int i = 0; i < 4; i++) oacc[i] = (f32x4){0.f, 0.f, 0.f, 0.f};
    float lsum = 0.f;

    const int NT = SEQ / 64;          // 32
    STAGE_K(0, 0);
    STAGE_K(1, 1);
    STAGE_V(0, 0);
    VMW(4); BARRIER();                // K(0) landed; K(1):2 + V(0):2 in flight

    int b3 = 0, b2 = 0;
    for (int t = 0; t < NT; t++) {
        if (t + 2 < NT) STAGE_K((t + 2) % 3, t + 2);
        if (t + 1 < NT) STAGE_V((t + 1) & 1, t + 1);

        f32x4 s[4];
        __builtin_amdgcn_s_setprio(1);
#pragma unroll
        for (int tt = 0; tt < 4; tt++) {
            bf16x8 af0 = *(const bf16x8*)(&Ks[b3][0][tt * 16 + l16][quad * 8]);
            bf16x8 af1 = *(const bf16x8*)(&Ks[b3][1][tt * 16 + l16][quad * 8]);
            f32x4 z = (f32x4){0.f, 0.f, 0.f, 0.f};
            z = __builtin_amdgcn_mfma_f32_16x16x32_bf16(af0, qf[0], z, 0, 0, 0);
            z = __builtin_amdgcn_mfma_f32_16x16x32_bf16(af1, qf[1], z, 0, 0, 0);
            s[tt] = z;
        }
        __builtin_amdgcn_s_setprio(0);

        if (t + 2 < NT)      { VMW(4); }
        else if (t + 1 < NT) { VMW(2); }
        else                 { VMW(0); }
        BARRIER();

        bf16x4 p[4];
#pragma unroll
        for (int tt = 0; tt < 4; tt++)
#pragma unroll
            for (int r = 0; r < 4; r++) {
                float pf = fast_exp2(s[tt][r]);
                lsum += pf;
                p[tt][r] = (bf16)pf;
            }

        __builtin_amdgcn_s_setprio(1);
#pragma unroll
        for (int tp = 0; tp < 2; tp++) {
            bf16x8 pa = __builtin_shufflevector(p[2 * tp], p[2 * tp + 1], 0, 1, 2, 3, 4, 5, 6, 7);
#pragma unroll
            for (int nt = 0; nt < 4; nt++) {
                bf16x8 vb = *(const bf16x8*)(&Vs[b2][tp][nt * 16 + l16][quad * 8]);
                oacc[nt] = __builtin_amdgcn_mfma_f32_16x16x32_bf16(pa, vb, oacc[nt], 0, 0, 0);
            }
        }
        __builtin_amdgcn_s_setprio(0);

        BARRIER();
        b3 = (b3 + 1) % 3;
        b2 ^= 1;
    }

#undef STAGE_K
#undef STAGE_V

    lsum += __shfl_xor(lsum, 16, 64);
    lsum += __shfl_xor(lsum, 32, 64);
    float invl[4];
#pragma unroll
    for (int r = 0; r < 4; r++)
        invl[r] = 1.0f / __shfl(lsum, quad * 4 + r, 16);

#pragma unroll
    for (int nt = 0; nt < 4; nt++)
#pragma unroll
        for (int r = 0; r < 4; r++)
            o[(size_t)(b * SEQ + q0 + quad * 4 + r) * D_MODEL + h * HDIM + nt * 16 + l16] =
                (bf16)(oacc[nt][r] * invl[r]);
}

// ---------------- launcher ----------------
extern "C" void kernel_launch(void* const* d_in, const int* in_sizes, int n_in,
                              void* d_out, int out_size, void* d_ws, size_t ws_size,
                              hipStream_t stream) {
    const float* x     = (const float*)d_in[0];
    const float* ln1_g = (const float*)d_in[1];
    const float* ln1_b = (const float*)d_in[2];
    const float* w_qkv = (const float*)d_in[3];
    const float* b_qkv = (const float*)d_in[4];
    const float* w_out = (const float*)d_in[5];
    const float* b_out = (const float*)d_in[6];
    const float* ln2_g = (const float*)d_in[7];
    const float* ln2_b = (const float*)d_in[8];
    const float* w_fc1 = (const float*)d_in[9];
    const float* b_fc1 = (const float*)d_in[10];
    const float* w_fc2 = (const float*)d_in[11];
    const float* b_fc2 = (const float*)d_in[12];
    float* out = (float*)d_out;

    uintptr_t ws = (uintptr_t)d_ws;
    bf16* wt_qkv = (bf16*)(ws + 0);                  //  6291456 B
    bf16* wt_out = (bf16*)(ws + 6291456);            //  2097152 B
    bf16* wt_fc1 = (bf16*)(ws + 8388608);            //  8388608 B
    bf16* wt_fc2 = (bf16*)(ws + 16777216);           //  8388608 B
    bf16* hbuf   = (bf16*)(ws + 25165824);           //  8388608 B
    bf16* vT     = hbuf;
    bf16* qkv    = (bf16*)(ws + 33554432);           // 25165824 B
    bf16* attn_o = (bf16*)(ws + 58720256);           //  8388608 B
    bf16* hgelu  = (bf16*)(ws + 33554432);           // 33554432 B (overlays dead qkv+attn_o)

    k_transpose_all<<<12288, dim3(32, 8), 0, stream>>>(w_qkv, w_out, w_fc1, w_fc2,
                                                       wt_qkv, wt_out, wt_fc1, wt_fc2);

    k_layernorm<<<NTOK, 256, 0, stream>>>(x, ln1_g, ln1_b, hbuf);

    // QKV: 256^2 fine-phase depth-3 (thinned barriers), grid 12x16 = 192 blocks
    k_gemm256<0><<<dim3(QKVN / 256, NTOK / 256), 512, 0, stream>>>(
        hbuf, wt_qkv, b_qkv, qkv, NTOK, QKVN, D_MODEL);

    k_vtrans<<<dim3(NTOK / 32, D_MODEL / 32), dim3(32, 8), 0, stream>>>(qkv, vT);

    k_attention2<<<dim3(SEQ / 64, BATCH * NHEAD), 256, 0, stream>>>(qkv, vT, attn_o);

    // out-proj: 128x64 fine-phase depth-3 (r10-proven), grid 16x32 = 512 blocks
    k_gemm128x64<<<dim3(D_MODEL / 64, NTOK / 128), 256, 0, stream>>>(
        attn_o, wt_out, b_out, x, out, NTOK, D_MODEL, D_MODEL);

    k_layernorm<<<NTOK, 256, 0, stream>>>(out, ln2_g, ln2_b, hbuf);

    // FC1: 256^2 fine-phase depth-3 (thinned barriers) + fast GELU, grid 16x16 = 256 blocks
    k_gemm256<1><<<dim3(FFDIM / 256, NTOK / 256), 512, 0, stream>>>(
        hbuf, wt_fc1, b_fc1, hgelu, NTOK, FFDIM, D_MODEL);

    // FC2: 128x64 fine-phase depth-3 (r10-proven 65.8us), grid 16x32 = 512 blocks, nt=64
    k_gemm128x64<<<dim3(D_MODEL / 64, NTOK / 128), 256, 0, stream>>>(
        hgelu, wt_fc2, b_fc2, out, out, NTOK, D_MODEL, FFDIM);
}